// Round 7
// baseline (218.174 us; speedup 1.0000x reference)
//
#include <hip/hip_runtime.h>
#include <stdint.h>

// GAT: B=8, N=1024, D=256, H=8, U=64, HU=512
// out = relu( softmax_k(mask(leaky(as[n,h]+an[k,h]))) @ f  + X@Wr + bias )

typedef __attribute__((ext_vector_type(8))) short short8;
typedef __attribute__((ext_vector_type(4))) float f32x4;

__device__ __forceinline__ unsigned short f32_to_bf16(float f) {
    unsigned int u = __float_as_uint(f);
    u = (u + 0x7fffu + ((u >> 16) & 1u)) >> 16;   // RNE
    return (unsigned short)u;
}
__device__ __forceinline__ float bf16_to_f32(unsigned short s) {
    return __uint_as_float(((unsigned int)s) << 16);
}
__device__ __forceinline__ void load_lds16(const unsigned short* g, unsigned short* l) {
    __builtin_amdgcn_global_load_lds(
        (const __attribute__((address_space(1))) unsigned int*)g,
        (__attribute__((address_space(3))) unsigned int*)l, 16, 0, 0);
}

// ---------------- packA: Abig[8192][768] = [bf16hi(X) | bf16hi(X) | bf16lo(X)]
__global__ __launch_bounds__(256) void pack_a(const float* __restrict__ X,
                                              unsigned short* __restrict__ Abig) {
    const int idx = blockIdx.x * 256 + threadIdx.x;   // 524288
    const int m  = idx >> 6;
    const int kg = (idx & 63) << 2;
    float4 x = *(const float4*)&X[m * 256 + kg];
    const float xs[4] = {x.x, x.y, x.z, x.w};
    union { unsigned short u[4]; uint64_t q; } hq, lq;
    #pragma unroll
    for (int i = 0; i < 4; i++) {
        unsigned short h = f32_to_bf16(xs[i]);
        hq.u[i] = h;
        lq.u[i] = f32_to_bf16(xs[i] - bf16_to_f32(h));
    }
    unsigned short* r = Abig + (size_t)m * 768;
    *(uint64_t*)(r + kg)       = hq.q;
    *(uint64_t*)(r + 256 + kg) = hq.q;
    *(uint64_t*)(r + 512 + kg) = lq.q;
}

// ---------------- packB: Bpack[n][k], n in [0,1024): (Wk cols | Wr cols), k in [0,768)
__global__ __launch_bounds__(256) void pack_b(const float* __restrict__ Wk,
                                              const float* __restrict__ Wr,
                                              unsigned short* __restrict__ Bpack) {
    const int idx = blockIdx.x * 256 + threadIdx.x;   // 786432
    const int n = idx / 768;
    const int k = idx - n * 768;
    const float* __restrict__ W = (n < 512) ? Wk : Wr;
    const int nc = n & 511;
    const float w = W[(k & 255) * 512 + nc];
    unsigned short h = f32_to_bf16(w);
    unsigned short o = (k >= 256 && k < 512) ? f32_to_bf16(w - bf16_to_f32(h)) : h;
    Bpack[idx] = o;
}

// ---------------- attn_ck: ck[d][o], o<8: kernel.aks, o>=8: kernel.akn
__global__ __launch_bounds__(512) void attn_ck(const float* __restrict__ kernel,
                                               const float* __restrict__ aks,
                                               const float* __restrict__ akn,
                                               float* __restrict__ ck) {
    const int d = blockIdx.x, j = threadIdx.x;
    const float kv = kernel[d * 512 + j];
    float a = kv * aks[j];
    float b = kv * akn[j];
    #pragma unroll
    for (int m = 32; m; m >>= 1) { a += __shfl_xor(a, m, 64); b += __shfl_xor(b, m, 64); }
    const int lane = j & 63, h = j >> 6;
    if (lane == 0) { ck[d * 16 + h] = a; ck[d * 16 + 8 + h] = b; }
}

// ---------------- attn_sa: saan[row][0..7]=as, [8..15]=an  =  X @ ck
__global__ __launch_bounds__(256) void attn_sa(const float* __restrict__ X,
                                               const float* __restrict__ ck,
                                               float* __restrict__ saan) {
    __shared__ __align__(16) float Xs[16][260];
    __shared__ __align__(16) float ckL[4096];
    const int t = threadIdx.x, row0 = blockIdx.x * 16;
    #pragma unroll
    for (int i = 0; i < 4; i++) {
        const int q = t + i * 256;                       // float4 index, 0..1023
        const int r = q >> 6, c4 = (q & 63) * 4;         // 64 float4s per row
        *(float4*)&Xs[r][c4] = *(const float4*)&X[(size_t)(row0 + r) * 256 + c4];
        *(float4*)&ckL[q * 4] = *(const float4*)&ck[q * 4];
    }
    __syncthreads();
    const int r = t >> 4, o = t & 15;
    float acc = 0.f;
    #pragma unroll 4
    for (int d = 0; d < 256; d++) acc = fmaf(Xs[r][d], ckL[d * 16 + o], acc);
    saan[(size_t)(row0 + r) * 16 + o] = acc;
}

// ---------------- Stage 1: bf16 MFMA GEMM  C[8192x1024] = Abig @ Bpack^T
// cols 0..511 -> featT[b][col][n] (bf16, ws, TRANSPOSED), cols 512..1023 -> resid (f32, d_out)
#define GK 768
__global__ __launch_bounds__(256) void gemm_bf16(const unsigned short* __restrict__ Ab,
                                                 const unsigned short* __restrict__ Bp,
                                                 unsigned short* __restrict__ featT,
                                                 float* __restrict__ outr) {
    __shared__ __align__(16) unsigned short As[128 * 32];  // [m][k]
    __shared__ __align__(16) unsigned short Bs[128 * 32];  // [n][k]
    const int tid = threadIdx.x;
    const int lane = tid & 63, wave = tid >> 6;
    const int wr = wave >> 1, wc = wave & 1;               // 2x2 waves of 64x64
    const int m0 = blockIdx.x * 128, n0 = blockIdx.y * 128;
    const int l15 = lane & 15, lhi = lane >> 4;

    f32x4 acc[4][4] = {};

    for (int k0 = 0; k0 < GK; k0 += 32) {
        #pragma unroll
        for (int i = 0; i < 2; i++) {
            const int s = tid + i * 256;
            const int row = s >> 2, kc = (s & 3) * 8;
            load_lds16(Ab + (size_t)(m0 + row) * GK + k0 + kc, &As[s * 8]);
            load_lds16(Bp + (size_t)(n0 + row) * GK + k0 + kc, &Bs[s * 8]);
        }
        asm volatile("s_waitcnt vmcnt(0)" ::: "memory");
        __syncthreads();
        short8 a[4], b[4];
        #pragma unroll
        for (int mi = 0; mi < 4; mi++)
            a[mi] = *(const short8*)&As[(wr * 64 + mi * 16 + l15) * 32 + lhi * 8];
        #pragma unroll
        for (int ni = 0; ni < 4; ni++)
            b[ni] = *(const short8*)&Bs[(wc * 64 + ni * 16 + l15) * 32 + lhi * 8];
        #pragma unroll
        for (int mi = 0; mi < 4; mi++)
            #pragma unroll
            for (int ni = 0; ni < 4; ni++)
                acc[mi][ni] = __builtin_amdgcn_mfma_f32_16x16x32_bf16(a[mi], b[ni], acc[mi][ni], 0, 0, 0);
        __syncthreads();
    }

    if (n0 < 512) {
        // write transposed: featT[b][col][n_local], 4 consecutive n per lane -> 8B store
        #pragma unroll
        for (int mi = 0; mi < 4; mi++)
            #pragma unroll
            for (int ni = 0; ni < 4; ni++) {
                const int col = n0 + wc * 64 + ni * 16 + l15;
                const int rbase = m0 + wr * 64 + mi * 16 + lhi * 4;
                const int bb = rbase >> 10, nl = rbase & 1023;
                union { unsigned short u[4]; uint64_t q; } pk;
                #pragma unroll
                for (int r = 0; r < 4; r++) pk.u[r] = f32_to_bf16(acc[mi][ni][r]);
                *(uint64_t*)&featT[(size_t)bb * 524288 + (size_t)col * 1024 + nl] = pk.q;
            }
    } else {
        #pragma unroll
        for (int mi = 0; mi < 4; mi++)
            #pragma unroll
            for (int ni = 0; ni < 4; ni++) {
                const int col = (n0 - 512) + wc * 64 + ni * 16 + l15;
                const int rbase = m0 + wr * 64 + mi * 16 + lhi * 4;
                #pragma unroll
                for (int r = 0; r < 4; r++)
                    outr[(size_t)(rbase + r) * 512 + col] = acc[mi][ni][r];
            }
    }
}

// ---------------- Stage 3: fused dense-P MFMA aggregation, barrier-free K-loop
// 16-row tiles: grid 512 (= 2 blocks/CU), 8 waves = 8 heads; rowsum via MFMA-with-ones
__global__ __launch_bounds__(512) void gat_mfma(
    const float* __restrict__ A, const unsigned short* __restrict__ featT,
    const float* __restrict__ saan, const float* __restrict__ bias,
    float* __restrict__ out) {
    __shared__ float an_s[1024][9];     // 36.9 KB; padded: conflict-free broadcast reads

    const int blk = blockIdx.x;
    const int b  = blk & 7;             // XCD-pinned: all blocks of batch b on XCD b
    const int n0 = (blk >> 3) * 16;
    const int t = threadIdx.x;
    const int w = t >> 6;               // wave = head
    const int lane = t & 63;
    const int l15 = lane & 15, lhi = lane >> 4;

    // stage an[k][h] for whole batch (single barrier; read-only afterwards)
    #pragma unroll
    for (int i = 0; i < 4; i++) {
        const int idx = i * 512 + t;     // 0..2047
        const int k = idx >> 1, half = (idx & 1) * 4;
        float4 v = *(const float4*)&saan[(size_t)(b * 1024 + k) * 16 + 8 + half];
        an_s[k][half + 0] = v.x; an_s[k][half + 1] = v.y;
        an_s[k][half + 2] = v.z; an_s[k][half + 3] = v.w;
    }
    const float as_r = saan[(size_t)(b * 1024 + n0 + l15) * 16 + w];

    // ones B-fragment (bf16 1.0) for rowsum MFMA
    short8 ones;
    #pragma unroll
    for (int i = 0; i < 8; i++) ones[i] = (short)0x3F80;

    f32x4 acc[4] = {};
    f32x4 accs = {};
    const unsigned short* __restrict__ fT = featT + (size_t)b * 524288;
    const float* __restrict__ Arow = A + (size_t)(b * 1024 + n0 + l15) * 1024;

    __syncthreads();   // an_s ready — last barrier before epilogue

    for (int k0 = 0; k0 < 1024; k0 += 32) {
        // lane's A-fragment direct from global: row n0+l15, k = k0+lhi*8 .. +7 (L1-shared)
        float4 a0 = *(const float4*)&Arow[k0 + lhi * 8];
        float4 a1 = *(const float4*)&Arow[k0 + lhi * 8 + 4];
        const float av[8] = {a0.x, a0.y, a0.z, a0.w, a1.x, a1.y, a1.z, a1.w};

        union { short8 s8; unsigned int u32[4]; } pa;
        #pragma unroll
        for (int q = 0; q < 4; q++) {
            float pv[2];
            #pragma unroll
            for (int d = 0; d < 2; d++) {
                const int j = q * 2 + d;
                float x = as_r + an_s[k0 + lhi * 8 + j][w];
                x = fmaxf(x, 0.2f * x);                 // leaky
                const float e = __expf(x);
                pv[d] = (av[j] > 0.5f) ? e : 0.f;
            }
            unsigned int pk;
            asm("v_cvt_pk_bf16_f32 %0, %1, %2" : "=v"(pk) : "v"(pv[0]), "v"(pv[1]));
            pa.u32[q] = pk;
        }
        // B-frags straight from featT (16B contiguous, L2-resident per XCD)
        short8 bf[4];
        #pragma unroll
        for (int ni = 0; ni < 4; ni++)
            bf[ni] = *(const short8*)&fT[(size_t)(w * 64 + ni * 16 + l15) * 1024 + k0 + lhi * 8];
        #pragma unroll
        for (int ni = 0; ni < 4; ni++)
            acc[ni] = __builtin_amdgcn_mfma_f32_16x16x32_bf16(pa.s8, bf[ni], acc[ni], 0, 0, 0);
        // rowsum of ROUNDED P in C-layout: accs[r] = sum_k P[lhi*4+r][k]
        accs = __builtin_amdgcn_mfma_f32_16x16x32_bf16(pa.s8, ones, accs, 0, 0, 0);
    }

    // epilogue: C-layout row = lhi*4 + r, col = ni*16 + l15; inv from accs (same layout)
    #pragma unroll
    for (int r = 0; r < 4; r++) {
        const int row_l = lhi * 4 + r;
        const float iv = 1.0f / accs[r];
        const size_t rb = (size_t)(b * 1024 + n0 + row_l) * 512 + w * 64;
        #pragma unroll
        for (int ni = 0; ni < 4; ni++) {
            const int col = ni * 16 + l15;
            const float v = fmaf(acc[ni][r], iv, out[rb + col] + bias[w * 64 + col]);
            out[rb + col] = fmaxf(v, 0.f);
        }
    }
}

extern "C" void kernel_launch(void* const* d_in, const int* in_sizes, int n_in,
                              void* d_out, int out_size, void* d_ws, size_t ws_size,
                              hipStream_t stream) {
    const float* X    = (const float*)d_in[0];
    const float* A    = (const float*)d_in[1];
    const float* Wk   = (const float*)d_in[2];
    const float* Wr   = (const float*)d_in[3];
    const float* aks  = (const float*)d_in[4];
    const float* akn  = (const float*)d_in[5];
    const float* bias = (const float*)d_in[6];
    float* out = (float*)d_out;

    // ws: featT 8MB + saan 0.5MB + ck 16KB + Abig 12MB + Bpack 1.5MB ~= 22MB
    unsigned short* featT = (unsigned short*)d_ws;            // [8][512][1024] bf16
    float* saan = (float*)(featT + (size_t)8 * 512 * 1024);   // [8192][16] f32
    float* ck   = saan + (size_t)8192 * 16;                   // [256][16] f32
    unsigned short* Abig  = (unsigned short*)(ck + 4096);     // [8192][768] bf16
    unsigned short* Bpack = Abig + (size_t)8192 * 768;        // [1024][768] bf16

    pack_a<<<2048, 256, 0, stream>>>(X, Abig);
    pack_b<<<3072, 256, 0, stream>>>(Wk, Wr, Bpack);
    attn_ck<<<256, 512, 0, stream>>>(Wk, aks, akn, ck);
    attn_sa<<<512, 256, 0, stream>>>(X, ck, saan);
    gemm_bf16<<<dim3(64, 8), 256, 0, stream>>>(Abig, Bpack, featT, out);
    gat_mfma<<<512, 512, 0, stream>>>(A, featT, saan, bias, out);
}

// Round 11
// 193.817 us; speedup vs baseline: 1.1257x; 1.1257x over previous
//
#include <hip/hip_runtime.h>
#include <stdint.h>

// GAT: B=8, N=1024, D=256, H=8, U=64, HU=512
// out = relu( softmax_k(mask(leaky(as[n,h]+an[k,h]))) @ f  + X@Wr + bias )

typedef __attribute__((ext_vector_type(8))) short short8;
typedef __attribute__((ext_vector_type(4))) float f32x4;

__device__ __forceinline__ unsigned short f32_to_bf16(float f) {
    unsigned int u = __float_as_uint(f);
    u = (u + 0x7fffu + ((u >> 16) & 1u)) >> 16;   // RNE
    return (unsigned short)u;
}
__device__ __forceinline__ float bf16_to_f32(unsigned short s) {
    return __uint_as_float(((unsigned int)s) << 16);
}
__device__ __forceinline__ void load_lds16(const unsigned short* g, unsigned short* l) {
    __builtin_amdgcn_global_load_lds(
        (const __attribute__((address_space(1))) unsigned int*)g,
        (__attribute__((address_space(3))) unsigned int*)l, 16, 0, 0);
}

// ---------------- packA: Abig[8192][768] = [bf16hi(X) | bf16hi(X) | bf16lo(X)]
__global__ __launch_bounds__(256) void pack_a(const float* __restrict__ X,
                                              unsigned short* __restrict__ Abig) {
    const int idx = blockIdx.x * 256 + threadIdx.x;   // 524288
    const int m  = idx >> 6;
    const int kg = (idx & 63) << 2;
    float4 x = *(const float4*)&X[m * 256 + kg];
    const float xs[4] = {x.x, x.y, x.z, x.w};
    union { unsigned short u[4]; uint64_t q; } hq, lq;
    #pragma unroll
    for (int i = 0; i < 4; i++) {
        unsigned short h = f32_to_bf16(xs[i]);
        hq.u[i] = h;
        lq.u[i] = f32_to_bf16(xs[i] - bf16_to_f32(h));
    }
    unsigned short* r = Abig + (size_t)m * 768;
    *(uint64_t*)(r + kg)       = hq.q;
    *(uint64_t*)(r + 256 + kg) = hq.q;
    *(uint64_t*)(r + 512 + kg) = lq.q;
}

// ---------------- packB: Bpack[n][k], n in [0,1024): (Wk cols | Wr cols), k in [0,768)
__global__ __launch_bounds__(256) void pack_b(const float* __restrict__ Wk,
                                              const float* __restrict__ Wr,
                                              unsigned short* __restrict__ Bpack) {
    const int idx = blockIdx.x * 256 + threadIdx.x;   // 786432
    const int n = idx / 768;
    const int k = idx - n * 768;
    const float* __restrict__ W = (n < 512) ? Wk : Wr;
    const int nc = n & 511;
    const float w = W[(k & 255) * 512 + nc];
    unsigned short h = f32_to_bf16(w);
    unsigned short o = (k >= 256 && k < 512) ? f32_to_bf16(w - bf16_to_f32(h)) : h;
    Bpack[idx] = o;
}

// ---------------- attn_ck: ck[d][o], o<8: kernel.aks, o>=8: kernel.akn
// scaled by log2(e) so downstream exp() becomes bare v_exp (2^x); leaky commutes
__global__ __launch_bounds__(512) void attn_ck(const float* __restrict__ kernel,
                                               const float* __restrict__ aks,
                                               const float* __restrict__ akn,
                                               float* __restrict__ ck) {
    const int d = blockIdx.x, j = threadIdx.x;
    const float kv = kernel[d * 512 + j];
    float a = kv * aks[j];
    float b = kv * akn[j];
    #pragma unroll
    for (int m = 32; m; m >>= 1) { a += __shfl_xor(a, m, 64); b += __shfl_xor(b, m, 64); }
    const int lane = j & 63, h = j >> 6;
    if (lane == 0) {
        ck[d * 16 + h]     = a * 1.4426950408889634f;
        ck[d * 16 + 8 + h] = b * 1.4426950408889634f;
    }
}

// ---------------- attn_sa: as_g[row][h] and an_Tg[b][h][n]  =  X @ ck (split layouts)
__global__ __launch_bounds__(256) void attn_sa(const float* __restrict__ X,
                                               const float* __restrict__ ck,
                                               float* __restrict__ as_g,
                                               float* __restrict__ an_Tg) {
    __shared__ __align__(16) float Xs[16][260];
    __shared__ __align__(16) float ckL[4096];
    const int t = threadIdx.x, row0 = blockIdx.x * 16;
    #pragma unroll
    for (int i = 0; i < 4; i++) {
        const int q = t + i * 256;                       // float4 index, 0..1023
        const int r = q >> 6, c4 = (q & 63) * 4;         // 64 float4s per row
        *(float4*)&Xs[r][c4] = *(const float4*)&X[(size_t)(row0 + r) * 256 + c4];
        *(float4*)&ckL[q * 4] = *(const float4*)&ck[q * 4];
    }
    __syncthreads();
    const int r = t >> 4, o = t & 15;
    float acc = 0.f;
    #pragma unroll 4
    for (int d = 0; d < 256; d++) acc = fmaf(Xs[r][d], ckL[d * 16 + o], acc);
    const int grow = row0 + r;
    if (o < 8)
        as_g[(size_t)grow * 8 + o] = acc;
    else
        an_Tg[((size_t)(grow >> 10) * 8 + (o - 8)) * 1024 + (grow & 1023)] = acc;
}

// ---------------- Stage 1: bf16 MFMA GEMM  C[8192x1024] = Abig @ Bpack^T
// cols 0..511 -> featT[b][col][n] (bf16, ws, TRANSPOSED), cols 512..1023 -> resid (f32, d_out)
#define GK 768
__global__ __launch_bounds__(256) void gemm_bf16(const unsigned short* __restrict__ Ab,
                                                 const unsigned short* __restrict__ Bp,
                                                 unsigned short* __restrict__ featT,
                                                 float* __restrict__ outr) {
    __shared__ __align__(16) unsigned short As[128 * 32];  // [m][k]
    __shared__ __align__(16) unsigned short Bs[128 * 32];  // [n][k]
    const int tid = threadIdx.x;
    const int lane = tid & 63, wave = tid >> 6;
    const int wr = wave >> 1, wc = wave & 1;               // 2x2 waves of 64x64
    const int m0 = blockIdx.x * 128, n0 = blockIdx.y * 128;
    const int l15 = lane & 15, lhi = lane >> 4;

    f32x4 acc[4][4] = {};

    for (int k0 = 0; k0 < GK; k0 += 32) {
        #pragma unroll
        for (int i = 0; i < 2; i++) {
            const int s = tid + i * 256;
            const int row = s >> 2, kc = (s & 3) * 8;
            load_lds16(Ab + (size_t)(m0 + row) * GK + k0 + kc, &As[s * 8]);
            load_lds16(Bp + (size_t)(n0 + row) * GK + k0 + kc, &Bs[s * 8]);
        }
        asm volatile("s_waitcnt vmcnt(0)" ::: "memory");
        __syncthreads();
        short8 a[4], b[4];
        #pragma unroll
        for (int mi = 0; mi < 4; mi++)
            a[mi] = *(const short8*)&As[(wr * 64 + mi * 16 + l15) * 32 + lhi * 8];
        #pragma unroll
        for (int ni = 0; ni < 4; ni++)
            b[ni] = *(const short8*)&Bs[(wc * 64 + ni * 16 + l15) * 32 + lhi * 8];
        #pragma unroll
        for (int mi = 0; mi < 4; mi++)
            #pragma unroll
            for (int ni = 0; ni < 4; ni++)
                acc[mi][ni] = __builtin_amdgcn_mfma_f32_16x16x32_bf16(a[mi], b[ni], acc[mi][ni], 0, 0, 0);
        __syncthreads();
    }

    if (n0 < 512) {
        // write transposed: featT[b][col][n_local], 4 consecutive n per lane -> 8B store
        #pragma unroll
        for (int mi = 0; mi < 4; mi++)
            #pragma unroll
            for (int ni = 0; ni < 4; ni++) {
                const int col = n0 + wc * 64 + ni * 16 + l15;
                const int rbase = m0 + wr * 64 + mi * 16 + lhi * 4;
                const int bb = rbase >> 10, nl = rbase & 1023;
                union { unsigned short u[4]; uint64_t q; } pk;
                #pragma unroll
                for (int r = 0; r < 4; r++) pk.u[r] = f32_to_bf16(acc[mi][ni][r]);
                *(uint64_t*)&featT[(size_t)bb * 524288 + (size_t)col * 1024 + nl] = pk.q;
            }
    } else {
        #pragma unroll
        for (int mi = 0; mi < 4; mi++)
            #pragma unroll
            for (int ni = 0; ni < 4; ni++) {
                const int col = (n0 - 512) + wc * 64 + ni * 16 + l15;
                const int rbase = m0 + wr * 64 + mi * 16 + lhi * 4;
                #pragma unroll
                for (int r = 0; r < 4; r++)
                    outr[(size_t)(rbase + r) * 512 + col] = acc[mi][ni][r];
            }
    }
}

// ---------------- Stage 3: fused dense-P MFMA aggregation, barrier-free K-loop
// 1024 threads, 32-row tile, 16 waves = (row-half, head); A as LDS bitmask
__global__ __launch_bounds__(1024) void gat_mfma2(
    const float* __restrict__ A, const unsigned short* __restrict__ featT,
    const float* __restrict__ as_g, const float* __restrict__ an_Tg,
    const float* __restrict__ bias, float* __restrict__ out) {
    __shared__ float an_T[8192];             // [h][k], 32 KB
    __shared__ unsigned int maskA[32][33];   // padded: bank = (row+wd)%32

    const int blk = blockIdx.x;
    const int b  = blk & 7;                  // XCD-pinned batch
    const int n0 = (blk >> 3) * 32;
    const int t = threadIdx.x;
    const int w16 = t >> 6;
    const int h = w16 & 7, half = w16 >> 3;
    const int lane = t & 63, l15 = lane & 15, lhi = lane >> 4;

    // stage an_T: 32KB contiguous copy
    {
        const float* __restrict__ src = an_Tg + (size_t)b * 8192;
        *(float4*)&an_T[t * 8]     = *(const float4*)&src[t * 8];
        *(float4*)&an_T[t * 8 + 4] = *(const float4*)&src[t * 8 + 4];
    }
    // stage A-tile as bitmask: thread -> (row, 32-bit word)
    {
        const int row = t >> 5, wd = t & 31;
        const float* __restrict__ ap = A + ((size_t)(b << 10) + n0 + row) * 1024 + wd * 32;
        unsigned int m = 0;
        #pragma unroll
        for (int i = 0; i < 8; i++) {
            float4 v = *(const float4*)&ap[i * 4];
            if (v.x > 0.5f) m |= 1u << (i * 4 + 0);
            if (v.y > 0.5f) m |= 1u << (i * 4 + 1);
            if (v.z > 0.5f) m |= 1u << (i * 4 + 2);
            if (v.w > 0.5f) m |= 1u << (i * 4 + 3);
        }
        maskA[row][wd] = m;
    }

    const int arow = half * 16 + l15;        // this lane's P-row within the 32-row tile
    const float as_r = as_g[((size_t)(b << 10) + n0 + arow) * 8 + h];

    short8 ones;
    #pragma unroll
    for (int i = 0; i < 8; i++) ones[i] = (short)0x3F80;   // bf16 1.0

    f32x4 acc[4] = {};
    f32x4 accs = {};
    const unsigned short* __restrict__ fT =
        featT + (size_t)b * 524288 + (size_t)(h * 64) * 1024;

    __syncthreads();   // the only barrier

    for (int k0 = 0; k0 < 1024; k0 += 32) {
        const unsigned int m = maskA[arow][k0 >> 5];
        const float* __restrict__ anp = &an_T[h * 1024 + k0 + lhi * 8];
        float4 an0 = *(const float4*)&anp[0];
        float4 an1 = *(const float4*)&anp[4];
        const float av[8] = {an0.x, an0.y, an0.z, an0.w, an1.x, an1.y, an1.z, an1.w};

        union { short8 s8; unsigned int u32[4]; } pa;
        #pragma unroll
        for (int q = 0; q < 4; q++) {
            float pv[2];
            #pragma unroll
            for (int d = 0; d < 2; d++) {
                const int j = q * 2 + d;
                float x = as_r + av[j];                     // already in log2e scale
                x = fmaxf(x, 0.2f * x);                     // leaky
                const float e = __builtin_amdgcn_exp2f(x);  // v_exp_f32 (2^x)
                pv[d] = (m & (1u << (lhi * 8 + j))) ? e : 0.f;
            }
            unsigned int pk;
            asm("v_cvt_pk_bf16_f32 %0, %1, %2" : "=v"(pk) : "v"(pv[0]), "v"(pv[1]));
            pa.u32[q] = pk;
        }
        short8 bf[4];
        #pragma unroll
        for (int ni = 0; ni < 4; ni++)
            bf[ni] = *(const short8*)&fT[(size_t)(ni * 16 + l15) * 1024 + k0 + lhi * 8];
        #pragma unroll
        for (int ni = 0; ni < 4; ni++)
            acc[ni] = __builtin_amdgcn_mfma_f32_16x16x32_bf16(pa.s8, bf[ni], acc[ni], 0, 0, 0);
        // rowsum of ROUNDED P (C-layout matches acc) -> normalization cancels rounding bias
        accs = __builtin_amdgcn_mfma_f32_16x16x32_bf16(pa.s8, ones, accs, 0, 0, 0);
    }

    // epilogue: C-layout row = half*16 + lhi*4 + r, col = h*64 + ni*16 + l15
    #pragma unroll
    for (int r = 0; r < 4; r++) {
        const int row_l = half * 16 + lhi * 4 + r;
        const float iv = 1.0f / accs[r];
        const size_t rb = ((size_t)(b << 10) + n0 + row_l) * 512 + h * 64;
        #pragma unroll
        for (int ni = 0; ni < 4; ni++) {
            const int col = ni * 16 + l15;
            const float v = fmaf(acc[ni][r], iv, out[rb + col] + bias[h * 64 + col]);
            out[rb + col] = fmaxf(v, 0.f);
        }
    }
}

extern "C" void kernel_launch(void* const* d_in, const int* in_sizes, int n_in,
                              void* d_out, int out_size, void* d_ws, size_t ws_size,
                              hipStream_t stream) {
    const float* X    = (const float*)d_in[0];
    const float* A    = (const float*)d_in[1];
    const float* Wk   = (const float*)d_in[2];
    const float* Wr   = (const float*)d_in[3];
    const float* aks  = (const float*)d_in[4];
    const float* akn  = (const float*)d_in[5];
    const float* bias = (const float*)d_in[6];
    float* out = (float*)d_out;

    // ws: featT 8MB + as_g 256KB + an_Tg 256KB + ck 16KB + Abig 12MB + Bpack 1.5MB ~= 22MB
    unsigned short* featT = (unsigned short*)d_ws;            // [8][512][1024] bf16
    float* as_g  = (float*)(featT + (size_t)8 * 512 * 1024);  // [8192][8] f32
    float* an_Tg = as_g + 65536;                              // [8][8][1024] f32
    float* ck    = an_Tg + 65536;                             // [256][16] f32
    unsigned short* Abig  = (unsigned short*)(ck + 4096);     // [8192][768] bf16
    unsigned short* Bpack = Abig + (size_t)8192 * 768;        // [1024][768] bf16

    pack_a<<<2048, 256, 0, stream>>>(X, Abig);
    pack_b<<<3072, 256, 0, stream>>>(Wk, Wr, Bpack);
    attn_ck<<<256, 512, 0, stream>>>(Wk, aks, akn, ck);
    attn_sa<<<512, 256, 0, stream>>>(X, ck, as_g, an_Tg);
    gemm_bf16<<<dim3(64, 8), 256, 0, stream>>>(Abig, Bpack, featT, out);
    gat_mfma2<<<256, 1024, 0, stream>>>(A, featT, as_g, an_Tg, bias, out);
}